// Round 8
// baseline (246.955 us; speedup 1.0000x reference)
//
#include <hip/hip_runtime.h>
#include <hip/hip_bf16.h>

typedef float f32x16 __attribute__((ext_vector_type(16)));
typedef int   i32x8  __attribute__((ext_vector_type(8)));
typedef int   i32x4  __attribute__((ext_vector_type(4)));

#define FP8_MAX 448.0f

// ---------------- helpers ----------------

__device__ __forceinline__ void g2l16(const void* g, void* l) {
    __builtin_amdgcn_global_load_lds(
        (const __attribute__((address_space(1))) void*)g,
        (__attribute__((address_space(3))) void*)l,
        16, 0, 0);
}

__device__ __forceinline__ float scale_from(float amax) {
    float s = FP8_MAX / (amax * 1.1f);
    return (amax == 0.0f) ? 1.0f : fminf(s, 10000.0f);
}

// ---------------- preprocessing (unchanged; at its BW roofline) ----------------

__global__ void init_kernel(unsigned* amax) {
    amax[0] = 0u;
    amax[1] = 0u;
}

__global__ void amax_fused_kernel(const float* __restrict__ x, size_t nx,
                                  const float* __restrict__ w, size_t nw,
                                  unsigned* __restrict__ amax, int xblocks) {
    const float* src;
    size_t n;
    unsigned* out;
    int bid, nb;
    if ((int)blockIdx.x < xblocks) {
        src = x; n = nx; out = amax; bid = blockIdx.x; nb = xblocks;
    } else {
        src = w; n = nw; out = amax + 1; bid = blockIdx.x - xblocks; nb = gridDim.x - xblocks;
    }
    float m = 0.0f;
    const size_t ustep = (size_t)blockDim.x * 4;
    const size_t chunkf = ustep * 8;
    size_t base = (size_t)bid * chunkf + (size_t)threadIdx.x * 4;
    const size_t gstride = (size_t)nb * chunkf;
    for (; base < n; base += gstride) {
        float4 v[8];
        #pragma unroll
        for (int u = 0; u < 8; ++u) {
            size_t idx = base + (size_t)u * ustep;
            float4 vv = {0.0f, 0.0f, 0.0f, 0.0f};
            if (idx < n) vv = *(const float4*)(src + idx);
            v[u] = vv;
        }
        #pragma unroll
        for (int u = 0; u < 8; ++u)
            m = fmaxf(m, fmaxf(fmaxf(fabsf(v[u].x), fabsf(v[u].y)),
                               fmaxf(fabsf(v[u].z), fabsf(v[u].w))));
    }
    #pragma unroll
    for (int off = 32; off > 0; off >>= 1)
        m = fmaxf(m, __shfl_xor(m, off));
    __shared__ float sm[4];
    if ((threadIdx.x & 63) == 0) sm[threadIdx.x >> 6] = m;
    __syncthreads();
    if (threadIdx.x == 0) {
        float mm = fmaxf(fmaxf(sm[0], sm[1]), fmaxf(sm[2], sm[3]));
        atomicMax(out, __float_as_uint(mm));
    }
}

__device__ __forceinline__ float qclamp(float v, float s) {
    return fminf(fmaxf(v * s, -FP8_MAX), FP8_MAX);
}

__global__ void quant_fused_kernel(const float* __restrict__ x, size_t nx,
                                   const float* __restrict__ w, size_t nw,
                                   const unsigned* __restrict__ amax,
                                   unsigned char* __restrict__ xq,
                                   unsigned char* __restrict__ wq, int xblocks) {
    const float* src;
    size_t n;
    unsigned char* dst;
    int bid, nb, sel;
    if ((int)blockIdx.x < xblocks) {
        src = x; n = nx; dst = xq; bid = blockIdx.x; nb = xblocks; sel = 0;
    } else {
        src = w; n = nw; dst = wq; bid = blockIdx.x - xblocks; nb = gridDim.x - xblocks; sel = 1;
    }
    const float s = scale_from(__uint_as_float(amax[sel]));
    const size_t ustep = (size_t)blockDim.x * 4;
    const size_t chunkf = ustep * 4;
    size_t base = (size_t)bid * chunkf + (size_t)threadIdx.x * 4;
    const size_t gstride = (size_t)nb * chunkf;
    for (; base < n; base += gstride) {
        float4 v[4];
        bool ok[4];
        #pragma unroll
        for (int u = 0; u < 4; ++u) {
            size_t idx = base + (size_t)u * ustep;
            ok[u] = idx < n;
            float4 vv = {0.0f, 0.0f, 0.0f, 0.0f};
            if (ok[u]) vv = *(const float4*)(src + idx);
            v[u] = vv;
        }
        #pragma unroll
        for (int u = 0; u < 4; ++u) {
            if (ok[u]) {
                int p = __builtin_amdgcn_cvt_pk_fp8_f32(qclamp(v[u].x, s), qclamp(v[u].y, s), 0, false);
                p = __builtin_amdgcn_cvt_pk_fp8_f32(qclamp(v[u].z, s), qclamp(v[u].w, s), p, true);
                *(unsigned*)(dst + base + (size_t)u * ustep) = (unsigned)p;
            }
        }
    }
}

// ---------------- GEMM: 128x256 tile, ring-3 LDS, 2 blocks/CU TLP + counted vmcnt ----
// Rounds 5-7 lesson: every 1-block/CU schedule (155-176us) loses to r3's
// 2-block TLP (140us) — at 2 waves/SIMD the CU can't fill latency from within
// a block. This kernel = r3's TLP geometry (128x256, 4 waves of 64x128,
// ~120 VGPR, grid 1024) + ring-3 dbuf with counted vmcnt (never drains to 0):
//   per iter: stage(t+2 -> slot (t+2)%3); vmcnt(6) [drains tile t, issued 2
//   iters (~2000cyc) earlier -> wait ~0]; barrier; 12x ds_read_b128; 8x
//   mfma_scale (compiler inserts fine-grained lgkm); barrier.
// WAR safety: stage targets slot of t-1, whose reads completed before the
// preceding barrier (each read is consumed by an MFMA that issued pre-barrier,
// and MFMA issue requires read completion via compiler lgkmcnt).
// LDS = 3 x (8KB A + 16KB B) = 72 KB -> 2 blocks/CU. launch_bounds(256,2).
#define BM 128
#define BN 256
#define BKB 64

__global__ __launch_bounds__(256, 2) void gemm_fp8_kernel(
    const unsigned char* __restrict__ Aq,   // [M][K] fp8
    const unsigned char* __restrict__ Bq,   // [N][K] fp8
    const float* __restrict__ bias,
    const unsigned* __restrict__ amax,
    float* __restrict__ out,
    int M, int N, int K) {
    __shared__ alignas(16) unsigned char sA[3][BM * BKB];   // 3 x 8 KB
    __shared__ alignas(16) unsigned char sB[3][BN * BKB];   // 3 x 16 KB

    const int tid = threadIdx.x;
    const int wave = tid >> 6;
    const int lane = tid & 63;
    const int r31 = lane & 31;
    const int half = lane >> 5;

    int nwg = (int)gridDim.x;
    int bid = (int)blockIdx.x;
    if ((nwg & 7) == 0) {
        int cpx = nwg >> 3;
        bid = (bid & 7) * cpx + (bid >> 3);
    }
    const int nbn = N / BN;
    const int brow = (bid / nbn) * BM;
    const int bcol = (bid % nbn) * BN;

    const int wr = (wave >> 1) * 64;     // wave row base (2M)
    const int wc = (wave & 1) * 128;     // wave col base (2N)

    f32x16 acc[2][4] = {};

    const int NT = K / BKB;              // 64
    const int j0 = tid * 16;

    auto stageA = [&](int slot, int t) {
        #pragma unroll
        for (int j = 0; j < 2; ++j) {
            int oo = j * 4096 + j0;
            int r = oo >> 6;                              // row 0..127
            int c = (oo & 63) ^ (((r >> 1) & 3) << 4);    // pre-swizzled source col
            g2l16(Aq + (size_t)(brow + r) * K + t * BKB + c,
                  &sA[slot][j * 4096 + wave * 1024]);
        }
    };
    auto stageB = [&](int slot, int t) {
        #pragma unroll
        for (int j = 0; j < 4; ++j) {
            int oo = j * 4096 + j0;
            int r = oo >> 6;                              // row 0..255
            int c = (oo & 63) ^ (((r >> 1) & 3) << 4);
            g2l16(Bq + (size_t)(bcol + r) * K + t * BKB + c,
                  &sB[slot][j * 4096 + wave * 1024]);
        }
    };
    auto rdA = [&](int slot, int row) -> i32x8 {
        const unsigned char* base = &sA[slot][row * BKB];
        int swz = ((row >> 1) & 3) << 4;
        int kb = half * 32;
        union { i32x8 v8; i32x4 v4[2]; } u;
        u.v4[0] = *(const i32x4*)(base + (kb ^ swz));
        u.v4[1] = *(const i32x4*)(base + ((kb + 16) ^ swz));
        return u.v8;
    };
    auto rdB = [&](int slot, int row) -> i32x8 {
        const unsigned char* base = &sB[slot][row * BKB];
        int swz = ((row >> 1) & 3) << 4;
        int kb = half * 32;
        union { i32x8 v8; i32x4 v4[2]; } u;
        u.v4[0] = *(const i32x4*)(base + (kb ^ swz));
        u.v4[1] = *(const i32x4*)(base + ((kb + 16) ^ swz));
        return u.v8;
    };

    #define MM(a, b, c) \
        c = __builtin_amdgcn_mfma_scale_f32_32x32x64_f8f6f4( \
            a, b, c, 0, 0, 0, 0x7f7f7f7f, 0, 0x7f7f7f7f)

    // prologue: stage tiles 0 and 1 (12 loads outstanding)
    stageA(0, 0); stageB(0, 0);
    stageA(1, 1); stageB(1, 1);

    int sr = 0;                          // slot of tile t
    for (int t = 0; t < NT; ++t) {
        int tt = t + 2;
        if (tt >= NT) tt -= NT;          // dummy re-stage into dead slot at tail
        int ss = sr + 2; if (ss >= 3) ss -= 3;
        stageA(ss, tt);
        stageB(ss, tt);
        // drains tile t (iter 0: tiles 0+1, prologue); leaves 6-12 in flight
        asm volatile("s_waitcnt vmcnt(6)" ::: "memory");
        __builtin_amdgcn_s_barrier();

        i32x8 a[2], b[4];
        #pragma unroll
        for (int m = 0; m < 2; ++m) a[m] = rdA(sr, wr + m * 32 + r31);
        #pragma unroll
        for (int n = 0; n < 4; ++n) b[n] = rdB(sr, wc + n * 32 + r31);
        #pragma unroll
        for (int m = 0; m < 2; ++m)
            #pragma unroll
            for (int n = 0; n < 4; ++n)
                MM(a[m], b[n], acc[m][n]);
        __builtin_amdgcn_s_barrier();    // all reads of tile t consumed before next stage

        sr = sr + 1; if (sr >= 3) sr = 0;
    }

    // epilogue: 32x32 C/D layout: col = lane&31, row = (reg&3) + 8*(reg>>2) + 4*(lane>>5)
    const float invx = 1.0f / scale_from(__uint_as_float(amax[0]));
    const float invw = 1.0f / scale_from(__uint_as_float(amax[1]));
    const float s2 = invx * invw;
    #pragma unroll
    for (int n = 0; n < 4; ++n) {
        int col = bcol + wc + n * 32 + r31;
        float bv = bias[col];
        #pragma unroll
        for (int m = 0; m < 2; ++m) {
            int rbase = brow + wr + m * 32 + half * 4;
            #pragma unroll
            for (int r = 0; r < 16; ++r) {
                int row = rbase + (r & 3) + 8 * (r >> 2);
                out[(size_t)row * N + col] = acc[m][n][r] * s2 + bv;
            }
        }
    }
    #undef MM
}

// ---------------- launch ----------------

extern "C" void kernel_launch(void* const* d_in, const int* in_sizes, int n_in,
                              void* d_out, int out_size, void* d_ws, size_t ws_size,
                              hipStream_t stream) {
    const float* x    = (const float*)d_in[0];
    const float* w    = (const float*)d_in[1];
    const float* bias = (const float*)d_in[2];
    float* out = (float*)d_out;

    const size_t nx = (size_t)in_sizes[0];
    const size_t nw = (size_t)in_sizes[1];
    const int N = in_sizes[2];
    const int K = (int)(nw / (size_t)N);
    const int M = (int)(nx / (size_t)K);

    unsigned* amax = (unsigned*)d_ws;
    unsigned char* xq = (unsigned char*)d_ws + 256;
    unsigned char* wq = xq + nx;

    const int TOTB = 2048;
    int xb = (int)((double)TOTB * (double)nx / (double)(nx + nw));
    if (xb < 1) xb = 1;
    if (xb > TOTB - 1) xb = TOTB - 1;

    init_kernel<<<1, 1, 0, stream>>>(amax);
    amax_fused_kernel<<<TOTB, 256, 0, stream>>>(x, nx, w, nw, amax, xb);
    quant_fused_kernel<<<TOTB, 256, 0, stream>>>(x, nx, w, nw, amax, xq, wq, xb);

    dim3 grid((M / BM) * (N / BN));
    gemm_fp8_kernel<<<grid, 256, 0, stream>>>(xq, wq, bias, amax, out, M, N, K);
}